// Round 7
// baseline (205.651 us; speedup 1.0000x reference)
//
#include <hip/hip_runtime.h>
#include <hip/hip_bf16.h>
#include <cmath>

// Single persistent fused kernel (512 blocks x 256 thr) + 1 tiny memset.
// R7: fold ada-RMSNorm into GEMM A-operand staging. gsl[c]=scale*gamma/rms is
// per-INPUT-channel, so W @ (gsl(.)x) = (W(.)gsl_cols) @ x: each GEMM block
// computes the gamma-MLP once into LDS (~1us redundant) and scales W during
// staging. x->bf16 transpose needs no stats -> phase A; x2->bf16 transpose
// fused into proj epilogue. Deletes both convx phases and 2 barriers:
//  A: weights->bf16 + stats1(x) + zero stats2 + xb=bf16(x)^T
//  C: qkv GEMM (gsl1-scaled W)   D: attention
//  E: proj GEMM + resid -> x2 fp32 AND xb2 bf16^T + stats2 atomics
//  G: mlp1 GEMM (gsl2-scaled W)  H: mlp2 GEMM + resid
// Barrier: relaxed arrive per XCD (s_getreg XCC_ID), last-per-XCD RELEASE RMW
// (one wbl2) on master, per-XCD go flag, relaxed polls (R6 protocol).
// First-touch audit: xb A->C; q/kv C->D; o_attn D->E; x2 E->H (same block =
// same XCD); xb2 E->G; m_buf G->H; stats via coherent-point atomics.

#define NPOS 4096
#define C_CH 192
#define NB   512

typedef __bf16 bf16x8 __attribute__((ext_vector_type(8)));
typedef __bf16 bf16x4 __attribute__((ext_vector_type(4)));
typedef float  f32x4  __attribute__((ext_vector_type(4)));

__device__ __forceinline__ float bflo(unsigned int u) {
    union { unsigned int i; float f; } c; c.i = u << 16; return c.f;
}
__device__ __forceinline__ float bfhi(unsigned int u) {
    union { unsigned int i; float f; } c; c.i = u & 0xffff0000u; return c.f;
}

// bar layout (uints): pop[x]=bar[x*16]; preArr[g]=bar[128+g*16];
// preMaster=bar[256]; preGo[g]=bar[272+g*16];
// data barrier i (i<5): base=512+i*512: arr[x]=base+x*16, master=base+128,
// go[x]=base+144+x*16.  Memset 3072 uints = 12KB per launch.

__device__ __forceinline__ void pre_sync(unsigned* bar, int grp) {
    __syncthreads();
    if (threadIdx.x == 0) {
        unsigned* arr    = bar + 128 + grp * 16;
        unsigned* master = bar + 256;
        unsigned* go     = bar + 272 + grp * 16;
        unsigned prev = __hip_atomic_fetch_add(arr, 1u, __ATOMIC_RELAXED,
                                               __HIP_MEMORY_SCOPE_AGENT);
        if (prev == 63u) {
            __hip_atomic_fetch_add(master, 1u, __ATOMIC_RELAXED,
                                   __HIP_MEMORY_SCOPE_AGENT);
            while (__hip_atomic_load(master, __ATOMIC_RELAXED,
                                     __HIP_MEMORY_SCOPE_AGENT) < 8u)
                __builtin_amdgcn_s_sleep(2);
            __hip_atomic_store(go, 1u, __ATOMIC_RELAXED, __HIP_MEMORY_SCOPE_AGENT);
        }
        while (__hip_atomic_load(go, __ATOMIC_RELAXED,
                                 __HIP_MEMORY_SCOPE_AGENT) == 0u)
            __builtin_amdgcn_s_sleep(2);
    }
    __syncthreads();
}

__device__ __forceinline__ void grid_sync(unsigned* bar, int idx, int xcc,
                                          unsigned myPop, unsigned nx) {
    __syncthreads();
    if (threadIdx.x == 0) {
        unsigned* base   = bar + 512 + idx * 512;
        unsigned* arr    = base + xcc * 16;
        unsigned* master = base + 128;
        unsigned* go     = base + 144 + xcc * 16;
        unsigned prev = __hip_atomic_fetch_add(arr, 1u, __ATOMIC_RELAXED,
                                               __HIP_MEMORY_SCOPE_AGENT);
        if (prev == myPop - 1u) {
            __hip_atomic_fetch_add(master, 1u, __ATOMIC_RELEASE,   // wbl2 here
                                   __HIP_MEMORY_SCOPE_AGENT);
            while (__hip_atomic_load(master, __ATOMIC_RELAXED,
                                     __HIP_MEMORY_SCOPE_AGENT) < nx)
                __builtin_amdgcn_s_sleep(2);
            __hip_atomic_store(go, 1u, __ATOMIC_RELAXED, __HIP_MEMORY_SCOPE_AGENT);
        }
        while (__hip_atomic_load(go, __ATOMIC_RELAXED,
                                 __HIP_MEMORY_SCOPE_AGENT) == 0u)
            __builtin_amdgcn_s_sleep(2);
    }
    __syncthreads();
}

// fp32 -> bf16, 1024 floats per unit (256 thr x float4)
__device__ __forceinline__ void conv_unit(const float* __restrict__ src,
                                          __bf16* __restrict__ dst, int base)
{
    int i = (base * 256 + (int)threadIdx.x) * 4;
    float4 v = *(const float4*)(src + i);
    bf16x4 o = { (__bf16)v.x, (__bf16)v.y, (__bf16)v.z, (__bf16)v.w };
    *(bf16x4*)(dst + i) = o;
}

// per-channel sum / sumsq of one channel (whole block)
__device__ void stats_unit(float* sm, const float* __restrict__ x,
                           float* __restrict__ sums, float* __restrict__ sumsq, int c)
{
    const float4* xc = (const float4*)(x + (size_t)c * NPOS);
    float a = 0.f, a2 = 0.f;
    for (int i = threadIdx.x; i < NPOS / 4; i += 256) {
        float4 v = xc[i];
        a  += v.x + v.y + v.z + v.w;
        a2 += v.x * v.x + v.y * v.y + v.z * v.z + v.w * v.w;
    }
    #pragma unroll
    for (int off = 32; off > 0; off >>= 1) {
        a  += __shfl_down(a, off);
        a2 += __shfl_down(a2, off);
    }
    float* ls = sm; float* ls2 = sm + 4;
    int wid = threadIdx.x >> 6;
    if ((threadIdx.x & 63) == 0) { ls[wid] = a; ls2[wid] = a2; }
    __syncthreads();
    if (threadIdx.x == 0) {
        float t = 0.f, t2 = 0.f;
        #pragma unroll
        for (int w = 0; w < 4; w++) { t += ls[w]; t2 += ls2[w]; }
        sums[c] = t; sumsq[c] = t2;
    }
    __syncthreads();
}

// transpose 16 positions of x [c][pos] fp32 -> xb [pos][192] bf16 (no scaling)
__device__ void transpose_unit(float* sm, const float* __restrict__ x,
                               __bf16* __restrict__ xb, int p0)
{
    float* lds = sm;   // 192*17 floats
    int t = threadIdx.x;
    for (int idx = t; idx < 192 * 4; idx += 256) {
        int row = idx >> 2, p4 = idx & 3;
        float4 v = *(const float4*)(x + (size_t)row * NPOS + p0 + p4 * 4);
        lds[row * 17 + p4 * 4 + 0] = v.x;
        lds[row * 17 + p4 * 4 + 1] = v.y;
        lds[row * 17 + p4 * 4 + 2] = v.z;
        lds[row * 17 + p4 * 4 + 3] = v.w;
    }
    __syncthreads();
    for (int idx = t; idx < 48 * 16; idx += 256) {
        int c4 = idx >> 4, p = idx & 15;
        bf16x4 o;
        #pragma unroll
        for (int j = 0; j < 4; j++) o[j] = (__bf16)lds[(c4 * 4 + j) * 17 + p];
        *(bf16x4*)(xb + (size_t)(p0 + p) * 192 + c4 * 4) = o;
    }
    __syncthreads();
}

// gamma-MLP -> gslOut[192] (LDS). scratch = 576 floats of LDS (aliases al).
__device__ void compute_gsl(float* scratch, float* gslOut,
    const float* __restrict__ sums, const float* __restrict__ sumsq,
    const float* __restrict__ scale,
    const __bf16* __restrict__ w1b, const float* __restrict__ b1,
    const __bf16* __restrict__ w2b, const float* __restrict__ b2)
{
    float* stats = scratch;        // 192
    float* h     = scratch + 192;  // 384
    int t = threadIdx.x;
    if (t < C_CH)
        stats[t] = __hip_atomic_load((const float*)&sums[t], __ATOMIC_RELAXED,
                                     __HIP_MEMORY_SCOPE_AGENT) * (1.0f / (float)NPOS);
    __syncthreads();
    for (int j = t; j < 384; j += 256) {
        float acc = b1[j];
        const __bf16* wr = w1b + (size_t)j * C_CH;
        #pragma unroll 4
        for (int c = 0; c < C_CH; c += 8) {
            bf16x8 w8 = *(const bf16x8*)(wr + c);
            acc += (float)w8[0] * stats[c]     + (float)w8[1] * stats[c + 1]
                 + (float)w8[2] * stats[c + 2] + (float)w8[3] * stats[c + 3]
                 + (float)w8[4] * stats[c + 4] + (float)w8[5] * stats[c + 5]
                 + (float)w8[6] * stats[c + 6] + (float)w8[7] * stats[c + 7];
        }
        h[j] = fmaxf(acc, 0.0f);
    }
    __syncthreads();
    if (t < C_CH) {
        float acc = b2[t];
        const __bf16* wr = w2b + (size_t)t * 384;
        #pragma unroll 4
        for (int j = 0; j < 384; j += 8) {
            bf16x8 w8 = *(const bf16x8*)(wr + j);
            acc += (float)w8[0] * h[j]     + (float)w8[1] * h[j + 1]
                 + (float)w8[2] * h[j + 2] + (float)w8[3] * h[j + 3]
                 + (float)w8[4] * h[j + 4] + (float)w8[5] * h[j + 5]
                 + (float)w8[6] * h[j + 6] + (float)w8[7] * h[j + 7];
        }
        float g = 1.0f / (1.0f + __expf(-acc));
        float sq = __hip_atomic_load((const float*)&sumsq[t], __ATOMIC_RELAXED,
                                     __HIP_MEMORY_SCOPE_AGENT);
        float rms = sqrtf(sq * (1.0f / (float)NPOS) + 1e-6f);
        gslOut[t] = scale[t] * g / rms;
    }
    __syncthreads();
}

// one 64x64 MFMA GEMM tile.
// EPI: 0=qkv scatter, 2=resid add, 3=gelu bf16^T, 4=resid add + stats atomics
//      + bf16^T copy (xb2o).  SCALEA: scale A-operand by gslLds[k] in staging.
template <int K, int EPI, bool SCALEA>
__device__ void gemm_tile(__bf16* al, __bf16* bl, const float* gslLds,
    int bx, int by,
    const __bf16* __restrict__ W, const float* __restrict__ bias,
    const __bf16* __restrict__ X, void* __restrict__ out,
    const float* __restrict__ resid, int M, __bf16* __restrict__ out_kv,
    float* __restrict__ s2sum, float* __restrict__ s2sq,
    __bf16* __restrict__ xb2o)
{
    constexpr int KC  = 192;
    constexpr int LDA = 200;
    int t    = threadIdx.x;
    int lane = t & 63;
    int wv   = t >> 6;
    int r16  = lane & 15;
    int quad = lane >> 4;
    int wvm  = wv >> 1;
    int wvn  = wv & 1;
    int mBase = by * 64;
    int nBase = bx * 64;

    f32x4 acc[2][2];
    #pragma unroll
    for (int i = 0; i < 2; i++)
        #pragma unroll
        for (int j = 0; j < 2; j++)
            acc[i][j] = (f32x4){0.f, 0.f, 0.f, 0.f};

    for (int k0 = 0; k0 < K; k0 += KC) {
        #pragma unroll
        for (int it = 0; it < 6; it++) {
            int c = it * 256 + t;
            int row = c / 24, off = c - row * 24;
            bf16x8 va = *(const bf16x8*)(W + (size_t)(mBase + row) * K + k0 + off * 8);
            if (SCALEA) {   // K==192, k0==0 in scaled uses
                #pragma unroll
                for (int j = 0; j < 8; j++)
                    va[j] = (__bf16)((float)va[j] * gslLds[off * 8 + j]);
            }
            *(bf16x8*)(al + row * LDA + off * 8) = va;
            bf16x8 vb = *(const bf16x8*)(X + (size_t)(nBase + row) * K + k0 + off * 8);
            *(bf16x8*)(bl + row * LDA + off * 8) = vb;
        }
        __syncthreads();
        #pragma unroll
        for (int ks = 0; ks < KC / 32; ks++) {
            bf16x8 a0 = *(const bf16x8*)(al + (wvm * 32 + r16) * LDA + ks * 32 + quad * 8);
            bf16x8 a1 = *(const bf16x8*)(al + (wvm * 32 + 16 + r16) * LDA + ks * 32 + quad * 8);
            bf16x8 b0 = *(const bf16x8*)(bl + (wvn * 32 + r16) * LDA + ks * 32 + quad * 8);
            bf16x8 b1 = *(const bf16x8*)(bl + (wvn * 32 + 16 + r16) * LDA + ks * 32 + quad * 8);
            acc[0][0] = __builtin_amdgcn_mfma_f32_16x16x32_bf16(a0, b0, acc[0][0], 0, 0, 0);
            acc[0][1] = __builtin_amdgcn_mfma_f32_16x16x32_bf16(a0, b1, acc[0][1], 0, 0, 0);
            acc[1][0] = __builtin_amdgcn_mfma_f32_16x16x32_bf16(a1, b0, acc[1][0], 0, 0, 0);
            acc[1][1] = __builtin_amdgcn_mfma_f32_16x16x32_bf16(a1, b1, acc[1][1], 0, 0, 0);
        }
        __syncthreads();
    }

    #pragma unroll
    for (int rt = 0; rt < 2; rt++) {
        int m0 = mBase + wvm * 32 + rt * 16 + quad * 4;
        float b0 = bias[m0], b1v = bias[m0 + 1], b2v = bias[m0 + 2], b3v = bias[m0 + 3];
        float ss[4] = {0.f, 0.f, 0.f, 0.f}, sq[4] = {0.f, 0.f, 0.f, 0.f};
        #pragma unroll
        for (int ct = 0; ct < 2; ct++) {
            int n = nBase + wvn * 32 + ct * 16 + r16;
            f32x4 a4 = acc[rt][ct];
            float g0 = a4[0] + b0, g1 = a4[1] + b1v, g2 = a4[2] + b2v, g3 = a4[3] + b3v;
            if (EPI == 0) {
                int sect = m0 / 192;
                int o0 = m0 - sect * 192;
                if (sect == 0) {
                    const float qs = 0.17677669529663687f;   // 32^-0.5 folded into q
                    *(float4*)((float*)out + (size_t)n * 192 + o0) =
                        make_float4(g0 * qs, g1 * qs, g2 * qs, g3 * qs);
                } else {
                    bf16x4 kvv = { (__bf16)g0, (__bf16)g1, (__bf16)g2, (__bf16)g3 };
                    *(bf16x4*)(out_kv + (size_t)n * 384 + (o0 >> 2) * 8 + (sect - 1) * 4) = kvv;
                }
            } else if (EPI == 2 || EPI == 4) {
                float* o = (float*)out;
                size_t i0 = (size_t)m0 * NPOS + n;
                float v0 = g0 + resid[i0];
                float v1 = g1 + resid[i0 + NPOS];
                float v2 = g2 + resid[i0 + 2 * NPOS];
                float v3 = g3 + resid[i0 + 3 * NPOS];
                o[i0] = v0; o[i0 + NPOS] = v1; o[i0 + 2 * NPOS] = v2; o[i0 + 3 * NPOS] = v3;
                if (EPI == 4) {
                    bf16x4 xv = { (__bf16)v0, (__bf16)v1, (__bf16)v2, (__bf16)v3 };
                    *(bf16x4*)(xb2o + (size_t)n * 192 + m0) = xv;
                    ss[0] += v0; sq[0] += v0 * v0;
                    ss[1] += v1; sq[1] += v1 * v1;
                    ss[2] += v2; sq[2] += v2 * v2;
                    ss[3] += v3; sq[3] += v3 * v3;
                }
            } else {
                bf16x4 v;
                v[0] = (__bf16)(0.5f * g0 * (1.0f + erff(g0 * 0.7071067811865475f)));
                v[1] = (__bf16)(0.5f * g1 * (1.0f + erff(g1 * 0.7071067811865475f)));
                v[2] = (__bf16)(0.5f * g2 * (1.0f + erff(g2 * 0.7071067811865475f)));
                v[3] = (__bf16)(0.5f * g3 * (1.0f + erff(g3 * 0.7071067811865475f)));
                *(bf16x4*)((__bf16*)out + (size_t)n * M + m0) = v;
            }
        }
        if (EPI == 4) {
            #pragma unroll
            for (int j = 0; j < 4; j++) {
                float s = ss[j], s2v = sq[j];
                #pragma unroll
                for (int off = 8; off >= 1; off >>= 1) {
                    s   += __shfl_down(s, off);
                    s2v += __shfl_down(s2v, off);
                }
                if (r16 == 0) {
                    atomicAdd(&s2sum[m0 + j], s);
                    atomicAdd(&s2sq[m0 + j], s2v);
                }
            }
        }
    }
}

// one attention unit = 8 (pos,head) pairs over the block's 256 threads
__device__ __forceinline__ void attn_unit(const float* __restrict__ q,
    const __bf16* __restrict__ kv, __bf16* __restrict__ o, int unit)
{
    int t = threadIdx.x;
    int pairIdx = unit * 8 + (t >> 5);
    int sg   = (t >> 3) & 3;
    int lane = t & 7;
    int pos = pairIdx / 6;
    int head = pairIdx - pos * 6;
    int wq = pos & 15;
    int hq = (pos >> 4) & 15;
    int dq = pos >> 8;
    int d0 = min(max(dq - 2, 0), 11);
    int h0 = min(max(hq - 2, 0), 11);
    int w0 = min(max(wq - 2, 0), 11);

    const __bf16* kvb = kv + head * 64 + lane * 8;
    float4 q4 = *(const float4*)(q + (size_t)pos * 192 + head * 32 + lane * 4);

    float l = 0.0f;
    float4 acc = make_float4(0.f, 0.f, 0.f, 0.f);

    for (int dh = sg; dh < 25; dh += 4) {
        int di = dh / 5;
        int hi = dh - di * 5;
        int np0 = (d0 + di) * 256 + (h0 + hi) * 16 + w0;
        const __bf16* p = kvb + (size_t)np0 * 384;
        #pragma unroll
        for (int wi = 0; wi < 5; wi++) {
            uint4 u = *(const uint4*)p;
            float s = q4.x * bflo(u.x) + q4.y * bfhi(u.x)
                    + q4.z * bflo(u.y) + q4.w * bfhi(u.y);
            s += __shfl_xor(s, 1);
            s += __shfl_xor(s, 2);
            s += __shfl_xor(s, 4);
            float pr = __expf(s);
            l += pr;
            acc.x += pr * bflo(u.z);
            acc.y += pr * bfhi(u.z);
            acc.z += pr * bflo(u.w);
            acc.w += pr * bfhi(u.w);
            p += 384;
        }
    }

    #pragma unroll
    for (int off = 8; off <= 16; off <<= 1) {
        l     += __shfl_xor(l, off);
        acc.x += __shfl_xor(acc.x, off);
        acc.y += __shfl_xor(acc.y, off);
        acc.z += __shfl_xor(acc.z, off);
        acc.w += __shfl_xor(acc.w, off);
    }

    if (sg == 0) {
        float rl = 1.0f / l;
        bf16x4 ov = { (__bf16)(acc.x * rl), (__bf16)(acc.y * rl),
                      (__bf16)(acc.z * rl), (__bf16)(acc.w * rl) };
        *(bf16x4*)(o + (size_t)pos * 192 + head * 32 + lane * 4) = ov;
    }
}

__global__ __launch_bounds__(256) void fused(
    const float* __restrict__ x, const float* __restrict__ scale1,
    const float* __restrict__ n1_w1, const float* __restrict__ n1_b1,
    const float* __restrict__ n1_w2, const float* __restrict__ n1_b2,
    const float* __restrict__ qkv_w, const float* __restrict__ qkv_b,
    const float* __restrict__ proj_w, const float* __restrict__ proj_b,
    const float* __restrict__ scale2,
    const float* __restrict__ n2_w1, const float* __restrict__ n2_b1,
    const float* __restrict__ n2_w2, const float* __restrict__ n2_b2,
    const float* __restrict__ mlp_w1, const float* __restrict__ mlp_b1,
    const float* __restrict__ mlp_w2, const float* __restrict__ mlp_b2,
    float* __restrict__ ws, float* __restrict__ x2)
{
    __shared__ __align__(16) char smraw[52224];   // al|bl (51200) + gsl (768) + pad
    __bf16* al     = (__bf16*)smraw;
    __bf16* bl     = al + 64 * 200;
    float*  smf    = (float*)smraw;
    float*  gslLds = (float*)(smraw + 51200);     // survives staging

    float*  q_buf   = ws;
    __bf16* kv_buf  = (__bf16*)(ws + 786432);
    __bf16* xb      = (__bf16*)(ws + 2359296);
    __bf16* o_attn  = (__bf16*)(ws + 2752512);
    __bf16* qkv_wb  = (__bf16*)(ws + 3145728);
    __bf16* proj_wb = qkv_wb + 110592;
    __bf16* m1_wb   = proj_wb + 36864;
    __bf16* m2_wb   = m1_wb + 147456;
    float*  sums1   = ws + 3366912;
    float*  sumsq1  = ws + 3367104;
    float*  sums2   = ws + 3367296;
    float*  sumsq2  = ws + 3367488;
    __bf16* n1w1b   = (__bf16*)(ws + 3367680);
    __bf16* n1w2b   = n1w1b + 73728;
    __bf16* n2w1b   = n1w2b + 73728;
    __bf16* n2w2b   = n2w1b + 73728;
    unsigned* bar   = (unsigned*)(ws + 3515136);   // 3072 uints used
    __bf16* m_buf   = (__bf16*)(ws + 3520512);     // [4096][768] bf16
    __bf16* xb2     = (__bf16*)(ws + 5093376);     // [4096][192] bf16

    int bid = blockIdx.x;
    int t   = threadIdx.x;

    // real XCD id (HW_REG_XCC_ID = id 20, offset 0, width 32 -> imm 63508)
    int xcc = __builtin_amdgcn_s_getreg(63508) & 7;

    // ---- population count + maintenance-free pre-barrier ----
    if (t == 0)
        __hip_atomic_fetch_add(bar + xcc * 16, 1u, __ATOMIC_RELAXED,
                               __HIP_MEMORY_SCOPE_AGENT);
    pre_sync(bar, bid & 7);
    unsigned myPop = 0, nx = 0;
    if (t == 0) {
        myPop = __hip_atomic_load(bar + xcc * 16, __ATOMIC_RELAXED,
                                  __HIP_MEMORY_SCOPE_AGENT);
        #pragma unroll
        for (int xi = 0; xi < 8; xi++)
            nx += (__hip_atomic_load(bar + xi * 16, __ATOMIC_RELAXED,
                                     __HIP_MEMORY_SCOPE_AGENT) > 0u) ? 1u : 0u;
    }

    // ---- phase A: weights->bf16 + stats1 + zero stats2 + xb=bf16(x)^T ----
    for (int u = bid; u < 1169; u += NB) {
        if      (u < 108)  conv_unit(qkv_w,  qkv_wb, u);
        else if (u < 144)  conv_unit(proj_w, proj_wb, u - 108);
        else if (u < 288)  conv_unit(mlp_w1, m1_wb, u - 144);
        else if (u < 432)  conv_unit(mlp_w2, m2_wb, u - 288);
        else if (u < 504)  conv_unit(n1_w1,  n1w1b, u - 432);
        else if (u < 576)  conv_unit(n1_w2,  n1w2b, u - 504);
        else if (u < 648)  conv_unit(n2_w1,  n2w1b, u - 576);
        else if (u < 720)  conv_unit(n2_w2,  n2w2b, u - 648);
        else if (u < 912)  stats_unit(smf, x, sums1, sumsq1, u - 720);
        else if (u == 912) {
            if (t < 192) {
                __hip_atomic_store(&sums2[t], 0.f, __ATOMIC_RELAXED,
                                   __HIP_MEMORY_SCOPE_AGENT);
                __hip_atomic_store(&sumsq2[t], 0.f, __ATOMIC_RELAXED,
                                   __HIP_MEMORY_SCOPE_AGENT);
            }
        }
        else               transpose_unit(smf, x, xb, (u - 913) * 16);
    }
    grid_sync(bar, 0, xcc, myPop, nx);

    // ---- phase C: qkv GEMM (gsl1-scaled W, 576 tiles) ----
    compute_gsl(smf, gslLds, sums1, sumsq1, scale1, n1w1b, n1_b1, n1w2b, n1_b2);
    for (int tile = bid; tile < 576; tile += NB)
        gemm_tile<192, 0, true>(al, bl, gslLds, tile & 63, tile >> 6,
                                qkv_wb, qkv_b, xb, (void*)q_buf,
                                nullptr, 576, kv_buf, nullptr, nullptr, nullptr);
    grid_sync(bar, 1, xcc, myPop, nx);

    // ---- phase D: attention (XCD-local mapping: block b -> slab b%8) ----
    {
        int base = (bid & 7) * 384 + (bid >> 3) * 6;
        for (int i = 0; i < 6; i++)
            attn_unit(q_buf, kv_buf, o_attn, base + i);
    }
    grid_sync(bar, 2, xcc, myPop, nx);

    // ---- phase E: proj GEMM + resid -> x2 fp32 + xb2 bf16^T + stats2 ----
    if (bid < 192)
        gemm_tile<192, 4, false>(al, bl, nullptr, bid & 63, bid >> 6,
                                 proj_wb, proj_b, o_attn, (void*)x2,
                                 x, 192, nullptr, sums2, sumsq2, xb2);
    grid_sync(bar, 3, xcc, myPop, nx);

    // ---- phase G: mlp1 GEMM (gsl2-scaled W, 768 tiles, gelu -> m_buf) ----
    compute_gsl(smf, gslLds, sums2, sumsq2, scale2, n2w1b, n2_b1, n2w2b, n2_b2);
    for (int tile = bid; tile < 768; tile += NB)
        gemm_tile<192, 3, true>(al, bl, gslLds, tile & 63, tile >> 6,
                                m1_wb, mlp_b1, xb2, (void*)m_buf,
                                nullptr, 768, nullptr, nullptr, nullptr, nullptr);
    grid_sync(bar, 4, xcc, myPop, nx);

    // ---- phase H: mlp2 GEMM + residual (in-place x2) ----
    if (bid < 192)
        gemm_tile<768, 2, false>(al, bl, nullptr, bid & 63, bid >> 6,
                                 m2_wb, mlp_b2, m_buf, (void*)x2,
                                 x2, 192, nullptr, nullptr, nullptr, nullptr);
}

// ---------------------------------------------------------------------------
extern "C" void kernel_launch(void* const* d_in, const int* in_sizes, int n_in,
                              void* d_out, int out_size, void* d_ws, size_t ws_size,
                              hipStream_t stream)
{
    const float* x      = (const float*)d_in[0];
    const float* scale1 = (const float*)d_in[1];
    const float* n1_w1  = (const float*)d_in[2];
    const float* n1_b1  = (const float*)d_in[3];
    const float* n1_w2  = (const float*)d_in[4];
    const float* n1_b2  = (const float*)d_in[5];
    const float* qkv_w  = (const float*)d_in[6];
    const float* qkv_b  = (const float*)d_in[7];
    const float* proj_w = (const float*)d_in[8];
    const float* proj_b = (const float*)d_in[9];
    const float* scale2 = (const float*)d_in[10];
    const float* n2_w1  = (const float*)d_in[11];
    const float* n2_b1  = (const float*)d_in[12];
    const float* n2_w2  = (const float*)d_in[13];
    const float* n2_b2  = (const float*)d_in[14];
    const float* mlp_w1 = (const float*)d_in[15];
    const float* mlp_b1 = (const float*)d_in[16];
    const float* mlp_w2 = (const float*)d_in[17];
    const float* mlp_b2 = (const float*)d_in[18];

    float* ws = (float*)d_ws;
    float* x2 = (float*)d_out;

    // zero pops + pre-barrier + 5 data barriers: 3072 uints = 12KB per replay
    hipMemsetAsync(ws + 3515136, 0, 3072 * sizeof(unsigned), stream);

    fused<<<NB, 256, 0, stream>>>(x, scale1, n1_w1, n1_b1, n1_w2, n1_b2,
                                  qkv_w, qkv_b, proj_w, proj_b,
                                  scale2, n2_w1, n2_b1, n2_w2, n2_b2,
                                  mlp_w1, mlp_b1, mlp_w2, mlp_b2,
                                  ws, x2);
}

// Round 8
// 192.829 us; speedup vs baseline: 1.0665x; 1.0665x over previous
//
#include <hip/hip_runtime.h>
#include <hip/hip_bf16.h>
#include <cmath>

// Single persistent fused kernel (512 blocks x 256 thr) + 1 tiny memset.
// R8: MFMA-tiled neighborhood attention. Unit = (4x4x4 pos-block, head);
// window union = fixed 8^3 region at clamp(Db-2,0,8). Per 128-kpos chunk:
// stage K[128][32]/V^T[32][128] LDS -> S=QK^T via mfma_16x16x32_bf16 (1 MFMA
// per 16x16 tile) -> separable mask (d per-wave, h per-lane, w 8-bit LUT) +
// exp -> P bf16 LDS -> PV MFMA (K=128). l accumulated per lane, reduced over
// r16 at end. 384 units on blocks 0..383. Everything else = R7:
//  A: weights->bf16 + stats1 + zero stats2 + xb=bf16(x)^T
//  C: qkv GEMM (gsl1-scaled W)  D: MFMA attention
//  E: proj GEMM + resid -> x2 + xb2 bf16^T + stats2   G: mlp1  H: mlp2+resid
// Barrier: R6 protocol (relaxed arrive per real XCD, one RELEASE RMW/XCD).

#define NPOS 4096
#define C_CH 192
#define NB   512

typedef __bf16 bf16x8 __attribute__((ext_vector_type(8)));
typedef __bf16 bf16x4 __attribute__((ext_vector_type(4)));
typedef float  f32x4  __attribute__((ext_vector_type(4)));

__device__ __forceinline__ void pre_sync(unsigned* bar, int grp) {
    __syncthreads();
    if (threadIdx.x == 0) {
        unsigned* arr    = bar + 128 + grp * 16;
        unsigned* master = bar + 256;
        unsigned* go     = bar + 272 + grp * 16;
        unsigned prev = __hip_atomic_fetch_add(arr, 1u, __ATOMIC_RELAXED,
                                               __HIP_MEMORY_SCOPE_AGENT);
        if (prev == 63u) {
            __hip_atomic_fetch_add(master, 1u, __ATOMIC_RELAXED,
                                   __HIP_MEMORY_SCOPE_AGENT);
            while (__hip_atomic_load(master, __ATOMIC_RELAXED,
                                     __HIP_MEMORY_SCOPE_AGENT) < 8u)
                __builtin_amdgcn_s_sleep(2);
            __hip_atomic_store(go, 1u, __ATOMIC_RELAXED, __HIP_MEMORY_SCOPE_AGENT);
        }
        while (__hip_atomic_load(go, __ATOMIC_RELAXED,
                                 __HIP_MEMORY_SCOPE_AGENT) == 0u)
            __builtin_amdgcn_s_sleep(2);
    }
    __syncthreads();
}

__device__ __forceinline__ void grid_sync(unsigned* bar, int idx, int xcc,
                                          unsigned myPop, unsigned nx) {
    __syncthreads();
    if (threadIdx.x == 0) {
        unsigned* base   = bar + 512 + idx * 512;
        unsigned* arr    = base + xcc * 16;
        unsigned* master = base + 128;
        unsigned* go     = base + 144 + xcc * 16;
        unsigned prev = __hip_atomic_fetch_add(arr, 1u, __ATOMIC_RELAXED,
                                               __HIP_MEMORY_SCOPE_AGENT);
        if (prev == myPop - 1u) {
            __hip_atomic_fetch_add(master, 1u, __ATOMIC_RELEASE,   // wbl2 here
                                   __HIP_MEMORY_SCOPE_AGENT);
            while (__hip_atomic_load(master, __ATOMIC_RELAXED,
                                     __HIP_MEMORY_SCOPE_AGENT) < nx)
                __builtin_amdgcn_s_sleep(2);
            __hip_atomic_store(go, 1u, __ATOMIC_RELAXED, __HIP_MEMORY_SCOPE_AGENT);
        }
        while (__hip_atomic_load(go, __ATOMIC_RELAXED,
                                 __HIP_MEMORY_SCOPE_AGENT) == 0u)
            __builtin_amdgcn_s_sleep(2);
    }
    __syncthreads();
}

__device__ __forceinline__ void conv_unit(const float* __restrict__ src,
                                          __bf16* __restrict__ dst, int base)
{
    int i = (base * 256 + (int)threadIdx.x) * 4;
    float4 v = *(const float4*)(src + i);
    bf16x4 o = { (__bf16)v.x, (__bf16)v.y, (__bf16)v.z, (__bf16)v.w };
    *(bf16x4*)(dst + i) = o;
}

__device__ void stats_unit(float* sm, const float* __restrict__ x,
                           float* __restrict__ sums, float* __restrict__ sumsq, int c)
{
    const float4* xc = (const float4*)(x + (size_t)c * NPOS);
    float a = 0.f, a2 = 0.f;
    for (int i = threadIdx.x; i < NPOS / 4; i += 256) {
        float4 v = xc[i];
        a  += v.x + v.y + v.z + v.w;
        a2 += v.x * v.x + v.y * v.y + v.z * v.z + v.w * v.w;
    }
    #pragma unroll
    for (int off = 32; off > 0; off >>= 1) {
        a  += __shfl_down(a, off);
        a2 += __shfl_down(a2, off);
    }
    float* ls = sm; float* ls2 = sm + 4;
    int wid = threadIdx.x >> 6;
    if ((threadIdx.x & 63) == 0) { ls[wid] = a; ls2[wid] = a2; }
    __syncthreads();
    if (threadIdx.x == 0) {
        float t = 0.f, t2 = 0.f;
        #pragma unroll
        for (int w = 0; w < 4; w++) { t += ls[w]; t2 += ls2[w]; }
        sums[c] = t; sumsq[c] = t2;
    }
    __syncthreads();
}

__device__ void transpose_unit(float* sm, const float* __restrict__ x,
                               __bf16* __restrict__ xb, int p0)
{
    float* lds = sm;   // 192*17 floats
    int t = threadIdx.x;
    for (int idx = t; idx < 192 * 4; idx += 256) {
        int row = idx >> 2, p4 = idx & 3;
        float4 v = *(const float4*)(x + (size_t)row * NPOS + p0 + p4 * 4);
        lds[row * 17 + p4 * 4 + 0] = v.x;
        lds[row * 17 + p4 * 4 + 1] = v.y;
        lds[row * 17 + p4 * 4 + 2] = v.z;
        lds[row * 17 + p4 * 4 + 3] = v.w;
    }
    __syncthreads();
    for (int idx = t; idx < 48 * 16; idx += 256) {
        int c4 = idx >> 4, p = idx & 15;
        bf16x4 o;
        #pragma unroll
        for (int j = 0; j < 4; j++) o[j] = (__bf16)lds[(c4 * 4 + j) * 17 + p];
        *(bf16x4*)(xb + (size_t)(p0 + p) * 192 + c4 * 4) = o;
    }
    __syncthreads();
}

__device__ void compute_gsl(float* scratch, float* gslOut,
    const float* __restrict__ sums, const float* __restrict__ sumsq,
    const float* __restrict__ scale,
    const __bf16* __restrict__ w1b, const float* __restrict__ b1,
    const __bf16* __restrict__ w2b, const float* __restrict__ b2)
{
    float* stats = scratch;        // 192
    float* h     = scratch + 192;  // 384
    int t = threadIdx.x;
    if (t < C_CH)
        stats[t] = __hip_atomic_load((const float*)&sums[t], __ATOMIC_RELAXED,
                                     __HIP_MEMORY_SCOPE_AGENT) * (1.0f / (float)NPOS);
    __syncthreads();
    for (int j = t; j < 384; j += 256) {
        float acc = b1[j];
        const __bf16* wr = w1b + (size_t)j * C_CH;
        #pragma unroll 4
        for (int c = 0; c < C_CH; c += 8) {
            bf16x8 w8 = *(const bf16x8*)(wr + c);
            acc += (float)w8[0] * stats[c]     + (float)w8[1] * stats[c + 1]
                 + (float)w8[2] * stats[c + 2] + (float)w8[3] * stats[c + 3]
                 + (float)w8[4] * stats[c + 4] + (float)w8[5] * stats[c + 5]
                 + (float)w8[6] * stats[c + 6] + (float)w8[7] * stats[c + 7];
        }
        h[j] = fmaxf(acc, 0.0f);
    }
    __syncthreads();
    if (t < C_CH) {
        float acc = b2[t];
        const __bf16* wr = w2b + (size_t)t * 384;
        #pragma unroll 4
        for (int j = 0; j < 384; j += 8) {
            bf16x8 w8 = *(const bf16x8*)(wr + j);
            acc += (float)w8[0] * h[j]     + (float)w8[1] * h[j + 1]
                 + (float)w8[2] * h[j + 2] + (float)w8[3] * h[j + 3]
                 + (float)w8[4] * h[j + 4] + (float)w8[5] * h[j + 5]
                 + (float)w8[6] * h[j + 6] + (float)w8[7] * h[j + 7];
        }
        float g = 1.0f / (1.0f + __expf(-acc));
        float sq = __hip_atomic_load((const float*)&sumsq[t], __ATOMIC_RELAXED,
                                     __HIP_MEMORY_SCOPE_AGENT);
        float rms = sqrtf(sq * (1.0f / (float)NPOS) + 1e-6f);
        gslOut[t] = scale[t] * g / rms;
    }
    __syncthreads();
}

template <int K, int EPI, bool SCALEA>
__device__ void gemm_tile(__bf16* al, __bf16* bl, const float* gslLds,
    int bx, int by,
    const __bf16* __restrict__ W, const float* __restrict__ bias,
    const __bf16* __restrict__ X, void* __restrict__ out,
    const float* __restrict__ resid, int M, __bf16* __restrict__ out_kv,
    float* __restrict__ s2sum, float* __restrict__ s2sq,
    __bf16* __restrict__ xb2o)
{
    constexpr int KC  = 192;
    constexpr int LDA = 200;
    int t    = threadIdx.x;
    int lane = t & 63;
    int wv   = t >> 6;
    int r16  = lane & 15;
    int quad = lane >> 4;
    int wvm  = wv >> 1;
    int wvn  = wv & 1;
    int mBase = by * 64;
    int nBase = bx * 64;

    f32x4 acc[2][2];
    #pragma unroll
    for (int i = 0; i < 2; i++)
        #pragma unroll
        for (int j = 0; j < 2; j++)
            acc[i][j] = (f32x4){0.f, 0.f, 0.f, 0.f};

    for (int k0 = 0; k0 < K; k0 += KC) {
        #pragma unroll
        for (int it = 0; it < 6; it++) {
            int c = it * 256 + t;
            int row = c / 24, off = c - row * 24;
            bf16x8 va = *(const bf16x8*)(W + (size_t)(mBase + row) * K + k0 + off * 8);
            if (SCALEA) {
                #pragma unroll
                for (int j = 0; j < 8; j++)
                    va[j] = (__bf16)((float)va[j] * gslLds[off * 8 + j]);
            }
            *(bf16x8*)(al + row * LDA + off * 8) = va;
            bf16x8 vb = *(const bf16x8*)(X + (size_t)(nBase + row) * K + k0 + off * 8);
            *(bf16x8*)(bl + row * LDA + off * 8) = vb;
        }
        __syncthreads();
        #pragma unroll
        for (int ks = 0; ks < KC / 32; ks++) {
            bf16x8 a0 = *(const bf16x8*)(al + (wvm * 32 + r16) * LDA + ks * 32 + quad * 8);
            bf16x8 a1 = *(const bf16x8*)(al + (wvm * 32 + 16 + r16) * LDA + ks * 32 + quad * 8);
            bf16x8 b0 = *(const bf16x8*)(bl + (wvn * 32 + r16) * LDA + ks * 32 + quad * 8);
            bf16x8 b1 = *(const bf16x8*)(bl + (wvn * 32 + 16 + r16) * LDA + ks * 32 + quad * 8);
            acc[0][0] = __builtin_amdgcn_mfma_f32_16x16x32_bf16(a0, b0, acc[0][0], 0, 0, 0);
            acc[0][1] = __builtin_amdgcn_mfma_f32_16x16x32_bf16(a0, b1, acc[0][1], 0, 0, 0);
            acc[1][0] = __builtin_amdgcn_mfma_f32_16x16x32_bf16(a1, b0, acc[1][0], 0, 0, 0);
            acc[1][1] = __builtin_amdgcn_mfma_f32_16x16x32_bf16(a1, b1, acc[1][1], 0, 0, 0);
        }
        __syncthreads();
    }

    #pragma unroll
    for (int rt = 0; rt < 2; rt++) {
        int m0 = mBase + wvm * 32 + rt * 16 + quad * 4;
        float b0 = bias[m0], b1v = bias[m0 + 1], b2v = bias[m0 + 2], b3v = bias[m0 + 3];
        float ss[4] = {0.f, 0.f, 0.f, 0.f}, sq[4] = {0.f, 0.f, 0.f, 0.f};
        #pragma unroll
        for (int ct = 0; ct < 2; ct++) {
            int n = nBase + wvn * 32 + ct * 16 + r16;
            f32x4 a4 = acc[rt][ct];
            float g0 = a4[0] + b0, g1 = a4[1] + b1v, g2 = a4[2] + b2v, g3 = a4[3] + b3v;
            if (EPI == 0) {
                int sect = m0 / 192;
                int o0 = m0 - sect * 192;
                if (sect == 0) {
                    const float qs = 0.17677669529663687f;   // 32^-0.5 folded into q
                    *(float4*)((float*)out + (size_t)n * 192 + o0) =
                        make_float4(g0 * qs, g1 * qs, g2 * qs, g3 * qs);
                } else {
                    bf16x4 kvv = { (__bf16)g0, (__bf16)g1, (__bf16)g2, (__bf16)g3 };
                    *(bf16x4*)(out_kv + (size_t)n * 384 + (o0 >> 2) * 8 + (sect - 1) * 4) = kvv;
                }
            } else if (EPI == 2 || EPI == 4) {
                float* o = (float*)out;
                size_t i0 = (size_t)m0 * NPOS + n;
                float v0 = g0 + resid[i0];
                float v1 = g1 + resid[i0 + NPOS];
                float v2 = g2 + resid[i0 + 2 * NPOS];
                float v3 = g3 + resid[i0 + 3 * NPOS];
                o[i0] = v0; o[i0 + NPOS] = v1; o[i0 + 2 * NPOS] = v2; o[i0 + 3 * NPOS] = v3;
                if (EPI == 4) {
                    bf16x4 xv = { (__bf16)v0, (__bf16)v1, (__bf16)v2, (__bf16)v3 };
                    *(bf16x4*)(xb2o + (size_t)n * 192 + m0) = xv;
                    ss[0] += v0; sq[0] += v0 * v0;
                    ss[1] += v1; sq[1] += v1 * v1;
                    ss[2] += v2; sq[2] += v2 * v2;
                    ss[3] += v3; sq[3] += v3 * v3;
                }
            } else {
                bf16x4 v;
                v[0] = (__bf16)(0.5f * g0 * (1.0f + erff(g0 * 0.7071067811865475f)));
                v[1] = (__bf16)(0.5f * g1 * (1.0f + erff(g1 * 0.7071067811865475f)));
                v[2] = (__bf16)(0.5f * g2 * (1.0f + erff(g2 * 0.7071067811865475f)));
                v[3] = (__bf16)(0.5f * g3 * (1.0f + erff(g3 * 0.7071067811865475f)));
                *(bf16x4*)((__bf16*)out + (size_t)n * M + m0) = v;
            }
        }
        if (EPI == 4) {
            #pragma unroll
            for (int j = 0; j < 4; j++) {
                float s = ss[j], s2v = sq[j];
                #pragma unroll
                for (int off = 8; off >= 1; off >>= 1) {
                    s   += __shfl_down(s, off);
                    s2v += __shfl_down(s2v, off);
                }
                if (r16 == 0) {
                    atomicAdd(&s2sum[m0 + j], s);
                    atomicAdd(&s2sq[m0 + j], s2v);
                }
            }
        }
    }
}

// ---------------------------------------------------------------------------
// MFMA neighborhood attention. Unit = (pos-block pb: 4x4x4, head).
// Region = 8^3 at (r0d,r0h,r0w) = clamp(B-2,0,8). 4 chunks of 128 kpos.
// LDS (bf16): Qs[64][40] | Ks[128][40] | Vt[32][136] | Ps[64][136] = 41.5KB.
// ---------------------------------------------------------------------------
__device__ void attn_mfma(char* smbase, const float* __restrict__ q,
                          const __bf16* __restrict__ kv, __bf16* __restrict__ o,
                          int pb, int head)
{
    __bf16* Qs = (__bf16*)smbase;        // [64][40]
    __bf16* Ks = Qs + 64 * 40;           // [128][40]
    __bf16* Vt = Ks + 128 * 40;          // [32][136] (V transposed: [ch][kpos])
    __bf16* Ps = Vt + 32 * 136;          // [64][136]

    int t = threadIdx.x;
    int wave = t >> 6, lane = t & 63, r16 = lane & 15, quad = lane >> 4;

    int Db = (pb >> 4) * 4, Hb = ((pb >> 2) & 3) * 4, Wb = (pb & 3) * 4;
    int r0d = min(max(Db - 2, 0), 8);
    int r0h = min(max(Hb - 2, 0), 8);
    int r0w = min(max(Wb - 2, 0), 8);

    // stage Q (fp32 q_buf -> bf16 LDS), 64 rows x 32 ch
    for (int idx = t; idx < 512; idx += 256) {
        int qr = idx >> 3, c4 = (idx & 7) * 4;
        int pos = (Db + (qr >> 4)) * 256 + (Hb + ((qr >> 2) & 3)) * 16 + (Wb + (qr & 3));
        float4 v = *(const float4*)(q + (size_t)pos * 192 + head * 32 + c4);
        bf16x4 b = { (__bf16)v.x, (__bf16)v.y, (__bf16)v.z, (__bf16)v.w };
        *(bf16x4*)(Qs + qr * 40 + c4) = b;
    }

    // separable masks: d per-wave, h per-lane(quad), w 8-bit LUT per reg
    int d0q = min(max(Db + wave - 2, 0), 11);
    int h0q = min(max(Hb + quad - 2, 0), 11);
    unsigned wm[4];
    #pragma unroll
    for (int reg = 0; reg < 4; reg++) {
        int w0q = min(max(Wb + reg - 2, 0), 11);
        unsigned m = 0;
        #pragma unroll
        for (int wk = 0; wk < 8; wk++) {
            int wa = r0w + wk;
            if (wa >= w0q && wa < w0q + 5) m |= (1u << wk);
        }
        wm[reg] = m;
    }

    float lpart[4] = {0.f, 0.f, 0.f, 0.f};
    f32x4 accO[2] = { (f32x4){0.f,0.f,0.f,0.f}, (f32x4){0.f,0.f,0.f,0.f} };
    int rowbase = wave * 16;

    for (int c = 0; c < 4; c++) {
        __syncthreads();   // prev-chunk PV readers done (and Q staged, c==0)
        // stage K / V^T for this 128-kpos chunk
        for (int idx = t; idx < 1024; idx += 256) {
            int l128 = idx >> 3, cp = idx & 7;
            int pos = (r0d + c * 2 + (l128 >> 6)) * 256
                    + (r0h + ((l128 >> 3) & 7)) * 16 + (r0w + (l128 & 7));
            uint4 u = *(const uint4*)(kv + (size_t)pos * 384 + head * 64 + cp * 8);
            uint2 kk; kk.x = u.x; kk.y = u.y;
            *(uint2*)(Ks + l128 * 40 + cp * 4) = kk;           // k4 packed
            unsigned short* vt0 = (unsigned short*)(Vt + (cp * 4) * 136 + l128);
            vt0[0]         = (unsigned short)(u.z & 0xffff);
            vt0[136]       = (unsigned short)(u.z >> 16);
            vt0[272]       = (unsigned short)(u.w & 0xffff);
            vt0[408]       = (unsigned short)(u.w >> 16);
        }
        __syncthreads();
        // QK^T: 8 tiles of 16(q)x16(kpos), K=32 in one MFMA each
        bf16x8 aq = *(const bf16x8*)(Qs + (rowbase + r16) * 40 + quad * 8);
        #pragma unroll
        for (int tn = 0; tn < 8; tn++) {
            bf16x8 bk = *(const bf16x8*)(Ks + (tn * 16 + r16) * 40 + quad * 8);
            f32x4 sc = __builtin_amdgcn_mfma_f32_16x16x32_bf16(
                           aq, bk, (f32x4){0.f,0.f,0.f,0.f}, 0, 0, 0);
            int local = tn * 16 + r16;
            int dka = r0d + c * 2 + (local >> 6);
            int hka = r0h + ((local >> 3) & 7);
            int wk  = local & 7;
            bool vdh = (dka >= d0q) && (dka < d0q + 5) &&
                       (hka >= h0q) && (hka < h0q + 5);
            #pragma unroll
            for (int reg = 0; reg < 4; reg++) {
                bool v = vdh && ((wm[reg] >> wk) & 1u);
                float p = v ? __expf(sc[reg]) : 0.f;
                lpart[reg] += p;
                Ps[(rowbase + quad * 4 + reg) * 136 + local] = (__bf16)p;
            }
        }
        __syncthreads();
        // PV: P[16 x 128] @ V[128 x 32] -> 2 ch-tiles x 4 k-steps
        #pragma unroll
        for (int tn = 0; tn < 2; tn++) {
            #pragma unroll
            for (int ks = 0; ks < 4; ks++) {
                bf16x8 pa = *(const bf16x8*)(Ps + (rowbase + r16) * 136 + ks * 32 + quad * 8);
                bf16x8 bv = *(const bf16x8*)(Vt + (tn * 16 + r16) * 136 + ks * 32 + quad * 8);
                accO[tn] = __builtin_amdgcn_mfma_f32_16x16x32_bf16(pa, bv, accO[tn], 0, 0, 0);
            }
        }
    }

    // reduce l over the 16 r16-lanes (C-cols); rows = quad*4+reg match PV out
    #pragma unroll
    for (int reg = 0; reg < 4; reg++) {
        #pragma unroll
        for (int off = 1; off < 16; off <<= 1)
            lpart[reg] += __shfl_xor(lpart[reg], off);
    }
    #pragma unroll
    for (int tn = 0; tn < 2; tn++) {
        #pragma unroll
        for (int reg = 0; reg < 4; reg++) {
            int qr = rowbase + quad * 4 + reg;
            int pos = (Db + (qr >> 4)) * 256 + (Hb + ((qr >> 2) & 3)) * 16 + (Wb + (qr & 3));
            o[(size_t)pos * 192 + head * 32 + tn * 16 + r16] =
                (__bf16)(accO[tn][reg] / lpart[reg]);
        }
    }
}

__global__ __launch_bounds__(256) void fused(
    const float* __restrict__ x, const float* __restrict__ scale1,
    const float* __restrict__ n1_w1, const float* __restrict__ n1_b1,
    const float* __restrict__ n1_w2, const float* __restrict__ n1_b2,
    const float* __restrict__ qkv_w, const float* __restrict__ qkv_b,
    const float* __restrict__ proj_w, const float* __restrict__ proj_b,
    const float* __restrict__ scale2,
    const float* __restrict__ n2_w1, const float* __restrict__ n2_b1,
    const float* __restrict__ n2_w2, const float* __restrict__ n2_b2,
    const float* __restrict__ mlp_w1, const float* __restrict__ mlp_b1,
    const float* __restrict__ mlp_w2, const float* __restrict__ mlp_b2,
    float* __restrict__ ws, float* __restrict__ x2)
{
    __shared__ __align__(16) char smraw[52224];   // al|bl (51200) + gsl (768) + pad
    __bf16* al     = (__bf16*)smraw;
    __bf16* bl     = al + 64 * 200;
    float*  smf    = (float*)smraw;
    float*  gslLds = (float*)(smraw + 51200);

    float*  q_buf   = ws;
    __bf16* kv_buf  = (__bf16*)(ws + 786432);
    __bf16* xb      = (__bf16*)(ws + 2359296);
    __bf16* o_attn  = (__bf16*)(ws + 2752512);
    __bf16* qkv_wb  = (__bf16*)(ws + 3145728);
    __bf16* proj_wb = qkv_wb + 110592;
    __bf16* m1_wb   = proj_wb + 36864;
    __bf16* m2_wb   = m1_wb + 147456;
    float*  sums1   = ws + 3366912;
    float*  sumsq1  = ws + 3367104;
    float*  sums2   = ws + 3367296;
    float*  sumsq2  = ws + 3367488;
    __bf16* n1w1b   = (__bf16*)(ws + 3367680);
    __bf16* n1w2b   = n1w1b + 73728;
    __bf16* n2w1b   = n1w2b + 73728;
    __bf16* n2w2b   = n2w1b + 73728;
    unsigned* bar   = (unsigned*)(ws + 3515136);   // 3072 uints used
    __bf16* m_buf   = (__bf16*)(ws + 3520512);     // [4096][768] bf16
    __bf16* xb2     = (__bf16*)(ws + 5093376);     // [4096][192] bf16

    int bid = blockIdx.x;
    int t   = threadIdx.x;

    // real XCD id (HW_REG_XCC_ID = id 20, offset 0, width 32 -> imm 63508)
    int xcc = __builtin_amdgcn_s_getreg(63508) & 7;

    if (t == 0)
        __hip_atomic_fetch_add(bar + xcc * 16, 1u, __ATOMIC_RELAXED,
                               __HIP_MEMORY_SCOPE_AGENT);
    pre_sync(bar, bid & 7);
    unsigned myPop = 0, nx = 0;
    if (t == 0) {
        myPop = __hip_atomic_load(bar + xcc * 16, __ATOMIC_RELAXED,
                                  __HIP_MEMORY_SCOPE_AGENT);
        #pragma unroll
        for (int xi = 0; xi < 8; xi++)
            nx += (__hip_atomic_load(bar + xi * 16, __ATOMIC_RELAXED,
                                     __HIP_MEMORY_SCOPE_AGENT) > 0u) ? 1u : 0u;
    }

    // ---- phase A: weights->bf16 + stats1 + zero stats2 + xb=bf16(x)^T ----
    for (int u = bid; u < 1169; u += NB) {
        if      (u < 108)  conv_unit(qkv_w,  qkv_wb, u);
        else if (u < 144)  conv_unit(proj_w, proj_wb, u - 108);
        else if (u < 288)  conv_unit(mlp_w1, m1_wb, u - 144);
        else if (u < 432)  conv_unit(mlp_w2, m2_wb, u - 288);
        else if (u < 504)  conv_unit(n1_w1,  n1w1b, u - 432);
        else if (u < 576)  conv_unit(n1_w2,  n1w2b, u - 504);
        else if (u < 648)  conv_unit(n2_w1,  n2w1b, u - 576);
        else if (u < 720)  conv_unit(n2_w2,  n2w2b, u - 648);
        else if (u < 912)  stats_unit(smf, x, sums1, sumsq1, u - 720);
        else if (u == 912) {
            if (t < 192) {
                __hip_atomic_store(&sums2[t], 0.f, __ATOMIC_RELAXED,
                                   __HIP_MEMORY_SCOPE_AGENT);
                __hip_atomic_store(&sumsq2[t], 0.f, __ATOMIC_RELAXED,
                                   __HIP_MEMORY_SCOPE_AGENT);
            }
        }
        else               transpose_unit(smf, x, xb, (u - 913) * 16);
    }
    grid_sync(bar, 0, xcc, myPop, nx);

    // ---- phase C: qkv GEMM (gsl1-scaled W, 576 tiles) ----
    compute_gsl(smf, gslLds, sums1, sumsq1, scale1, n1w1b, n1_b1, n1w2b, n1_b2);
    for (int tile = bid; tile < 576; tile += NB)
        gemm_tile<192, 0, true>(al, bl, gslLds, tile & 63, tile >> 6,
                                qkv_wb, qkv_b, xb, (void*)q_buf,
                                nullptr, 576, kv_buf, nullptr, nullptr, nullptr);
    grid_sync(bar, 1, xcc, myPop, nx);

    // ---- phase D: MFMA attention (384 units) ----
    if (bid < 384)
        attn_mfma(smraw, q_buf, kv_buf, o_attn, bid / 6, bid % 6);
    grid_sync(bar, 2, xcc, myPop, nx);

    // ---- phase E: proj GEMM + resid -> x2 fp32 + xb2 bf16^T + stats2 ----
    if (bid < 192)
        gemm_tile<192, 4, false>(al, bl, nullptr, bid & 63, bid >> 6,
                                 proj_wb, proj_b, o_attn, (void*)x2,
                                 x, 192, nullptr, sums2, sumsq2, xb2);
    grid_sync(bar, 3, xcc, myPop, nx);

    // ---- phase G: mlp1 GEMM (gsl2-scaled W, 768 tiles, gelu -> m_buf) ----
    compute_gsl(smf, gslLds, sums2, sumsq2, scale2, n2w1b, n2_b1, n2w2b, n2_b2);
    for (int tile = bid; tile < 768; tile += NB)
        gemm_tile<192, 3, true>(al, bl, gslLds, tile & 63, tile >> 6,
                                m1_wb, mlp_b1, xb2, (void*)m_buf,
                                nullptr, 768, nullptr, nullptr, nullptr, nullptr);
    grid_sync(bar, 4, xcc, myPop, nx);

    // ---- phase H: mlp2 GEMM + residual (in-place x2) ----
    if (bid < 192)
        gemm_tile<768, 2, false>(al, bl, nullptr, bid & 63, bid >> 6,
                                 m2_wb, mlp_b2, m_buf, (void*)x2,
                                 x2, 192, nullptr, nullptr, nullptr, nullptr);
}

// ---------------------------------------------------------------------------
extern "C" void kernel_launch(void* const* d_in, const int* in_sizes, int n_in,
                              void* d_out, int out_size, void* d_ws, size_t ws_size,
                              hipStream_t stream)
{
    const float* x      = (const float*)d_in[0];
    const float* scale1 = (const float*)d_in[1];
    const float* n1_w1  = (const float*)d_in[2];
    const float* n1_b1  = (const float*)d_in[3];
    const float* n1_w2  = (const float*)d_in[4];
    const float* n1_b2  = (const float*)d_in[5];
    const float* qkv_w  = (const float*)d_in[6];
    const float* qkv_b  = (const float*)d_in[7];
    const float* proj_w = (const float*)d_in[8];
    const float* proj_b = (const float*)d_in[9];
    const float* scale2 = (const float*)d_in[10];
    const float* n2_w1  = (const float*)d_in[11];
    const float* n2_b1  = (const float*)d_in[12];
    const float* n2_w2  = (const float*)d_in[13];
    const float* n2_b2  = (const float*)d_in[14];
    const float* mlp_w1 = (const float*)d_in[15];
    const float* mlp_b1 = (const float*)d_in[16];
    const float* mlp_w2 = (const float*)d_in[17];
    const float* mlp_b2 = (const float*)d_in[18];

    float* ws = (float*)d_ws;
    float* x2 = (float*)d_out;

    hipMemsetAsync(ws + 3515136, 0, 3072 * sizeof(unsigned), stream);

    fused<<<NB, 256, 0, stream>>>(x, scale1, n1_w1, n1_b1, n1_w2, n1_b2,
                                  qkv_w, qkv_b, proj_w, proj_b,
                                  scale2, n2_w1, n2_b1, n2_w2, n2_b2,
                                  mlp_w1, mlp_b1, mlp_w2, mlp_b2,
                                  ws, x2);
}